// Round 6
// baseline (77.483 us; speedup 1.0000x reference)
//
#include <hip/hip_runtime.h>

// Problem geometry (fixed by the reference):
//   x : (2, 8, 512, 512) f32, gm : (2, 1, 512, 512) f32
//   out = concat( bg:(2,8,512,512,16), on:(2,1,512,512,16) ) f32
// Key insight: hg==i, wg==j exactly -> splat is 1-D along r only; every
// output voxel is written by exactly one pixel. Pure streaming-write kernel.
//
// R6: EXACTLY the R1 structure (best so far, 67.75us) with one change:
// nontemporal stores (nt bit) so the 302MB streaming output doesn't
// allocate/thrash L2+L3 (302MB > 256MB L3) and fight the gm/x read set.
// Single-variable experiment vs R1.

#define HW      (512 * 512)           // 262144 = 2^18
#define NPIX    (2 * HW)              // 524288 pixels total
#define BG_SIZE (2 * 8 * HW * 16)     // 67108864 floats

typedef float f32x4 __attribute__((ext_vector_type(4)));

__global__ __launch_bounds__(256) void splat_r_kernel(
    const float* __restrict__ x,
    const float* __restrict__ gm,
    float* __restrict__ out)
{
    // 4 threads per pixel; thread owns r-chunk q (4 floats, 16B).
    int g     = blockIdx.x * 256 + threadIdx.x;
    int pixel = g >> 2;          // (n*HW + i*512 + j)
    int q     = g & 3;

    int n   = pixel >> 18;       // HW = 2^18
    int rem = pixel & (HW - 1);  // i*512 + j

    // r-splat weights
    float pr  = gm[pixel] * 15.0f;
    float r0f = floorf(pr);
    float t   = pr - r0f;
    int   r0  = (int)r0f;
    int   i0  = min(max(r0,     0), 15);
    int   i1  = min(max(r0 + 1, 0), 15);
    float w0  = 1.0f - t;

    int rbase = q * 4;
    // statically-built weight vector for this thread's 4 r-slots
    f32x4 w;
    w.x = ((rbase + 0) == i0 ? w0 : 0.0f) + ((rbase + 0) == i1 ? t : 0.0f);
    w.y = ((rbase + 1) == i0 ? w0 : 0.0f) + ((rbase + 1) == i1 ? t : 0.0f);
    w.z = ((rbase + 2) == i0 ? w0 : 0.0f) + ((rbase + 2) == i1 ? t : 0.0f);
    w.w = ((rbase + 3) == i0 ? w0 : 0.0f) + ((rbase + 3) == i1 ? t : 0.0f);

    // bg channels: out[(((n*8+c)*HW + rem)*16) + rbase .. +3]
    const float* xp = x + (n * 8) * HW + rem;
    #pragma unroll
    for (int c = 0; c < 8; ++c) {
        float v  = xp[c * HW];
        f32x4 o  = v * w;
        __builtin_nontemporal_store(o,
            (f32x4*)(out + (((size_t)(n * 8 + c) * HW + rem) * 16 + rbase)));
    }

    // ones channel -> on[(pixel*16) + rbase .. +3] after bg block
    __builtin_nontemporal_store(w,
        (f32x4*)(out + BG_SIZE + ((size_t)pixel * 16 + rbase)));
}

extern "C" void kernel_launch(void* const* d_in, const int* in_sizes, int n_in,
                              void* d_out, int out_size, void* d_ws, size_t ws_size,
                              hipStream_t stream) {
    const float* x  = (const float*)d_in[0];
    const float* gm = (const float*)d_in[1];
    float* out = (float*)d_out;

    const int total_threads = NPIX * 4;            // 2,097,152
    const int block = 256;
    const int grid  = total_threads / block;       // 8192
    splat_r_kernel<<<grid, block, 0, stream>>>(x, gm, out);
}

// Round 7
// 66.108 us; speedup vs baseline: 1.1721x; 1.1721x over previous
//
#include <hip/hip_runtime.h>

// Problem geometry (fixed by the reference):
//   x : (2, 8, 512, 512) f32, gm : (2, 1, 512, 512) f32
//   out = concat( bg:(2,8,512,512,16), on:(2,1,512,512,16) ) f32
// Key insight: hg==i, wg==j exactly -> splat is 1-D along r only; every
// output voxel is written by exactly one pixel. Pure streaming-write kernel.
//
// R7: exact revert to R1 (best: 67.75us). Experiments R3-R6 showed every
// structural alternative (grid-stride, plane-major, 2x-batch, nontemporal)
// is neutral-to-worse; regular full-line stores through L2 win. 302MB write
// + 19MB read at observed mixed-stream rate ~4.7-4.9 TB/s effective is the
// practical ceiling for this op on MI355X.

#define HW      (512 * 512)           // 262144 = 2^18
#define NPIX    (2 * HW)              // 524288 pixels total
#define BG_SIZE (2 * 8 * HW * 16)     // 67108864 floats

typedef float f32x4 __attribute__((ext_vector_type(4)));

__global__ __launch_bounds__(256) void splat_r_kernel(
    const float* __restrict__ x,
    const float* __restrict__ gm,
    float* __restrict__ out)
{
    // 4 threads per pixel; thread owns r-chunk q (4 floats, 16B).
    int g     = blockIdx.x * 256 + threadIdx.x;
    int pixel = g >> 2;          // (n*HW + i*512 + j)
    int q     = g & 3;

    int n   = pixel >> 18;       // HW = 2^18
    int rem = pixel & (HW - 1);  // i*512 + j

    // r-splat weights
    float pr  = gm[pixel] * 15.0f;
    float r0f = floorf(pr);
    float t   = pr - r0f;
    int   r0  = (int)r0f;
    int   i0  = min(max(r0,     0), 15);
    int   i1  = min(max(r0 + 1, 0), 15);
    float w0  = 1.0f - t;

    int rbase = q * 4;
    // statically-built weight vector for this thread's 4 r-slots
    f32x4 w;
    w.x = ((rbase + 0) == i0 ? w0 : 0.0f) + ((rbase + 0) == i1 ? t : 0.0f);
    w.y = ((rbase + 1) == i0 ? w0 : 0.0f) + ((rbase + 1) == i1 ? t : 0.0f);
    w.z = ((rbase + 2) == i0 ? w0 : 0.0f) + ((rbase + 2) == i1 ? t : 0.0f);
    w.w = ((rbase + 3) == i0 ? w0 : 0.0f) + ((rbase + 3) == i1 ? t : 0.0f);

    // bg channels: out[(((n*8+c)*HW + rem)*16) + rbase .. +3]
    const float* xp = x + (n * 8) * HW + rem;
    #pragma unroll
    for (int c = 0; c < 8; ++c) {
        float v  = xp[c * HW];
        f32x4 o  = v * w;
        *(f32x4*)(out + (((size_t)(n * 8 + c) * HW + rem) * 16 + rbase)) = o;
    }

    // ones channel -> on[(pixel*16) + rbase .. +3] after bg block
    *(f32x4*)(out + BG_SIZE + ((size_t)pixel * 16 + rbase)) = w;
}

extern "C" void kernel_launch(void* const* d_in, const int* in_sizes, int n_in,
                              void* d_out, int out_size, void* d_ws, size_t ws_size,
                              hipStream_t stream) {
    const float* x  = (const float*)d_in[0];
    const float* gm = (const float*)d_in[1];
    float* out = (float*)d_out;

    const int total_threads = NPIX * 4;            // 2,097,152
    const int block = 256;
    const int grid  = total_threads / block;       // 8192
    splat_r_kernel<<<grid, block, 0, stream>>>(x, gm, out);
}